// Round 18
// baseline (357.702 us; speedup 1.0000x reference)
//
#include <hip/hip_runtime.h>

// VectorQuantizer: X [16384][128] f32, E [128][8192] f32
// out (f32 flat): quantized [16384*128], encodings [16384*8192], indices [16384], loss [1]
// R18: BLOCK-level role split in one grid (barriers are block-scoped, so fill
// blocks free-run while compute blocks run their LDS-staged barrier pipeline):
//   bid%3<2 -> compute block (LDS-staged MFMA, ZERO enc stores, -> bestws)
//   bid%3=2 -> fill block (pure NT-store stream, 2MB contiguous stripe)
// R17 lesson: direct-L2 B-frags are request-rate-bound (195us compute-alone);
// LDS staging with coalesced loads is mandatory. R14 lesson: wave-level split
// fails only because of the shared block barrier -- blocks fix that.
#define D 128
#define K 8192
#define N 16384
#define BM 32                 // rows per compute block (512 compute blocks)
#define BN 128                // codebook cols per chunk
#define NCH (K / BN)          // 64
#define GRP 4                 // chunks per gate-group
#define THREADS 256
#define CAND_CAP 1024
#define DELTA 0.5f
#define RMIN_INIT 0xFF800000u // fsort(+inf); NOT 0xFFFFFFFF (decodes to NaN)

typedef __attribute__((ext_vector_type(4))) float f32x4;
typedef __attribute__((ext_vector_type(16))) float f32x16;
typedef __attribute__((ext_vector_type(8))) short short8;

__device__ __forceinline__ unsigned short f2bf(float f) {
    unsigned int b = __float_as_uint(f);
    return (unsigned short)((b + 0x7FFFu + ((b >> 16) & 1u)) >> 16);
}
__device__ __forceinline__ unsigned int fsort(float f) {
    unsigned int b = __float_as_uint(f);
    return b ^ ((unsigned int)((int)b >> 31) | 0x80000000u);
}
__device__ __forceinline__ float funsort(unsigned int u) {
    return __uint_as_float((u & 0x80000000u) ? (u ^ 0x80000000u) : ~u);
}

__device__ __forceinline__ void lds_barrier() {
    asm volatile("s_waitcnt lgkmcnt(0)" ::: "memory");
    __builtin_amdgcn_s_barrier();
}

// ---- prep: E -> bf16 transposed e1t[k][d], f32 transposed e2t[k][d], enorm ----
__global__ __launch_bounds__(256) void prep_kernel(const float* __restrict__ E,
        unsigned short* __restrict__ e1t, float* __restrict__ e2t,
        float* __restrict__ enorm) {
    __shared__ float esum[8][32];
    const int t = threadIdx.x;
    const int kl = t & 31, dg = t >> 5;
    const int k = blockIdx.x * 32 + kl;
    float s = 0.f;
    __align__(16) unsigned short tmpb[16];
    __align__(16) float tmpf[16];
#pragma unroll
    for (int j = 0; j < 16; ++j) {
        float v = E[(size_t)(dg * 16 + j) * K + k];
        s += v * v;
        tmpb[j] = f2bf(v);
        tmpf[j] = v;
    }
    *(f32x4*)(e1t + (size_t)k * D + dg * 16) = *(const f32x4*)tmpb;
    *(f32x4*)(e1t + (size_t)k * D + dg * 16 + 8) = *(const f32x4*)(tmpb + 8);
    if (e2t) {
#pragma unroll
        for (int q = 0; q < 4; ++q)
            *(f32x4*)(e2t + (size_t)k * D + dg * 16 + 4 * q) = *(const f32x4*)(tmpf + 4 * q);
    }
    esum[dg][kl] = s;
    __syncthreads();
    if (t < 32) {
        float e = 0.f;
#pragma unroll
        for (int g = 0; g < 8; ++g) e += esum[g][t];
        enorm[blockIdx.x * 32 + t] = e;
    }
}

template<int E2T>
__global__ __launch_bounds__(THREADS) void mega_kernel(
        const float* __restrict__ X, const float* __restrict__ E,
        const unsigned short* __restrict__ e1t, const float* __restrict__ e2t,
        const float* __restrict__ enorm, float* __restrict__ enc,
        unsigned long long* __restrict__ bestws) {
    const int bid = blockIdx.x;
    const int role = bid % 3;
    const int t = threadIdx.x;

    if (role == 2) {
        // ======== FILL BLOCK: pure NT-store stream, 2 MB contiguous ========
        const int fid = bid / 3;                       // 0..255
        f32x4* stripe = (f32x4*)enc + (size_t)fid * 131072;
        const f32x4 z = {0.f, 0.f, 0.f, 0.f};
        for (int i = 0; i < 512; ++i)
            __builtin_nontemporal_store(z, stripe + i * 256 + t);
        return;
    }

    // ======== COMPUTE BLOCK: LDS-staged MFMA sweep, ZERO enc stores ========
    __shared__ __align__(16) unsigned short b_s[2][BN * D];   // 64 KB, XOR-swizzled
    __shared__ unsigned long long cand[CAND_CAP];             // 8 KB
    __shared__ unsigned long long best[BM];
    __shared__ unsigned int rmin[BM];
    __shared__ int candn;

    const int cid = (bid / 3) * 2 + role;              // 0..511
    const int wid = t >> 6, l = t & 63;
    const int l31 = l & 31, lh = l >> 5;
    const int wn = wid;                                // 4 waves, 32 cols each
    const int rowbase = cid * BM;

    if (t < BM) { rmin[t] = RMIN_INIT; best[t] = ~0ull; }
    if (t == 0) candn = 0;

    // A fragments: bf16(x) for the block's 32 rows
    short8 afr[8];
    {
        const int row = rowbase + l31;
#pragma unroll
        for (int ks = 0; ks < 8; ++ks) {
            const float* xp = X + (size_t)row * D + ks * 16 + lh * 8;
            f32x4 v0 = *(const f32x4*)xp;
            f32x4 v1 = *(const f32x4*)(xp + 4);
            short8 a;
            a[0] = (short)f2bf(v0[0]); a[1] = (short)f2bf(v0[1]);
            a[2] = (short)f2bf(v0[2]); a[3] = (short)f2bf(v0[3]);
            a[4] = (short)f2bf(v1[0]); a[5] = (short)f2bf(v1[1]);
            a[6] = (short)f2bf(v1[2]); a[7] = (short)f2bf(v1[3]);
            afr[ks] = a;
        }
    }

    f32x4 sreg[8];
    {   // prologue: stage chunk 0 into buf 0 (coalesced f32x4 loads)
        const f32x4* gs = (const f32x4*)e1t;
#pragma unroll
        for (int i = 0; i < 8; ++i) sreg[i] = gs[t + THREADS * i];
#pragma unroll
        for (int i = 0; i < 8; ++i) {
            int unit = t + THREADS * i;
            int c = unit >> 4, slot = unit & 15;
            *(f32x4*)((char*)&b_s[0][0] + c * 256 + ((slot ^ (c & 15)) << 4)) = sreg[i];
        }
    }

    int cur = 0;
    for (int cg = 0; cg < NCH / GRP; ++cg) {
        float dsave[GRP][16];   // unrolled -> registers
#pragma unroll
        for (int g = 0; g < GRP; ++g) {
            const int ch = cg * GRP + g;
            if (ch + 1 < NCH) {
                const f32x4* gs = (const f32x4*)(e1t + (size_t)(ch + 1) * BN * D);
#pragma unroll
                for (int i = 0; i < 8; ++i) sreg[i] = gs[t + THREADS * i];
            }
            lds_barrier();   // buf[cur] ready

            const int c = wn * 32 + l31;
            const float en = enorm[ch * BN + c];   // no stores in stream -> safe

            f32x16 acc;
#pragma unroll
            for (int r = 0; r < 16; ++r) acc[r] = 0.f;
#pragma unroll
            for (int ks = 0; ks < 8; ++ks) {
                const int slot = ks * 2 + lh;
                short8 bf = *(const short8*)((const char*)&b_s[cur][0] + c * 256 +
                                             ((slot ^ (c & 15)) << 4));
                acc = __builtin_amdgcn_mfma_f32_32x32x16_bf16(afr[ks], bf, acc, 0, 0, 0);
            }
#pragma unroll
            for (int r = 0; r < 16; ++r)
                dsave[g][r] = fmaf(-2.f, acc[r], en);   // d~ = en - 2*sim

            if (ch + 1 < NCH) {
#pragma unroll
                for (int i = 0; i < 8; ++i) {
                    int unit = t + THREADS * i;
                    int c2 = unit >> 4, slot = unit & 15;
                    *(f32x4*)((char*)&b_s[cur ^ 1][0] + c2 * 256 +
                              ((slot ^ (c2 & 15)) << 4)) = sreg[i];
                }
            }
            cur ^= 1;
        }

        // ---- per-group gate: ONE shuffle reduce per 4 chunks ----
        float lmin[16];
#pragma unroll
        for (int r = 0; r < 16; ++r)
            lmin[r] = fminf(fminf(dsave[0][r], dsave[1][r]),
                            fminf(dsave[2][r], dsave[3][r]));
#pragma unroll
        for (int m = 1; m <= 16; m <<= 1)
#pragma unroll
            for (int r = 0; r < 16; ++r)
                lmin[r] = fminf(lmin[r], __shfl_xor(lmin[r], m, 64));

        float thrv[16];
#pragma unroll
        for (int q = 0; q < 4; ++q) {
            const int base = 8 * q + 4 * lh;
            uint4 rv = *(const uint4*)&rmin[base];
            thrv[4 * q + 0] = funsort(rv.x);
            thrv[4 * q + 1] = funsort(rv.y);
            thrv[4 * q + 2] = funsort(rv.z);
            thrv[4 * q + 3] = funsort(rv.w);
        }

#pragma unroll
        for (int r = 0; r < 16; ++r) {
            const int ro = (r & 3) + 8 * (r >> 2) + 4 * lh;
            const float te = fminf(thrv[r], lmin[r]) + DELTA;
#pragma unroll
            for (int g = 0; g < GRP; ++g) {
                if (dsave[g][r] < te) {
                    const int col = (cg * GRP + g) * BN + wn * 32 + l31;
                    int ci = atomicAdd(&candn, 1);
                    if (ci < CAND_CAP)
                        cand[ci] = ((unsigned long long)fsort(dsave[g][r]) << 32) |
                                   ((unsigned long long)ro << 13) | (unsigned)col;
                }
            }
            if (l31 == 0 && lmin[r] < thrv[r])
                atomicMin(&rmin[ro], fsort(lmin[r]));
        }
    }

    __syncthreads();   // cand/rmin final

    // ---- exact f32 verification ----
    {
        int n = candn; if (n > CAND_CAP) n = CAND_CAP;
        for (int i = wid; i < n; i += 4) {
            const unsigned long long e = cand[i];
            const float dta = funsort((unsigned int)(e >> 32));
            const int ro = (int)((e >> 13) & 63u);
            const int col = (int)(e & 8191u);
            if (dta < funsort(rmin[ro]) + DELTA) {
                const int row = rowbase + ro;
                float x0 = X[(size_t)row * D + l];
                float x1 = X[(size_t)row * D + 64 + l];
                float e0, e1;
                if (E2T) {
                    e0 = e2t[(size_t)col * D + l];
                    e1 = e2t[(size_t)col * D + 64 + l];
                } else {
                    e0 = E[(size_t)l * K + col];
                    e1 = E[(size_t)(l + 64) * K + col];
                }
                float s = x0 * e0 + x1 * e1;
#pragma unroll
                for (int m = 1; m <= 32; m <<= 1) s += __shfl_xor(s, m, 64);
                if (l == 0) {
                    float dtx = enorm[col] - 2.f * s;
                    atomicMin(&best[ro],
                        ((unsigned long long)fsort(dtx) << 32) | (unsigned)col);
                }
            }
        }
    }
    __syncthreads();

    if (t < BM) bestws[rowbase + t] = best[t];
}

// ---- finish: indices, 1.0 scatter (stream-ordered after fill), quantized,
//      loss partials ----
template<int E2T>
__global__ __launch_bounds__(256) void finish_kernel(const float* __restrict__ X,
        const float* __restrict__ E, const float* __restrict__ e2t,
        const unsigned long long* __restrict__ bestws, float* __restrict__ out,
        float* __restrict__ partials) {
    const int t = threadIdx.x;
    const int rl = t >> 4, s = t & 15;
    const int row = blockIdx.x * 16 + rl;
    float* qout = out;
    float* enc = out + (size_t)N * D;
    float* idxout = enc + (size_t)N * K;
    const int k = (int)(bestws[row] & 8191ull);
    const float* xp = X + (size_t)row * D + s * 8;
    f32x4 xv0 = *(const f32x4*)xp;
    f32x4 xv1 = *(const f32x4*)(xp + 4);
    f32x4 q0, q1;
    float part = 0.f;
#pragma unroll
    for (int j = 0; j < 4; ++j) {
        float e0, e1;
        if (E2T) {
            e0 = e2t[(size_t)k * D + s * 8 + j];
            e1 = e2t[(size_t)k * D + s * 8 + 4 + j];
        } else {
            e0 = E[(size_t)(s * 8 + j) * K + k];
            e1 = E[(size_t)(s * 8 + 4 + j) * K + k];
        }
        float d0 = e0 - xv0[j];
        q0[j] = xv0[j] + d0; part += d0 * d0;
        float d1 = e1 - xv1[j];
        q1[j] = xv1[j] + d1; part += d1 * d1;
    }
    *(f32x4*)(qout + (size_t)row * D + s * 8) = q0;
    *(f32x4*)(qout + (size_t)row * D + s * 8 + 4) = q1;
#pragma unroll
    for (int m = 1; m <= 8; m <<= 1) part += __shfl_xor(part, m, 64);
    __shared__ float rr[16];
    if (s == 0) {
        idxout[row] = (float)k;
        enc[(size_t)row * K + k] = 1.0f;
        rr[rl] = part;
    }
    __syncthreads();
    if (t == 0) {
        float sum = 0.f;
#pragma unroll
        for (int i = 0; i < 16; ++i) sum += rr[i];
        partials[blockIdx.x] = sum;
    }
}

__global__ __launch_bounds__(256) void loss_kernel(const float* __restrict__ partials,
                                                   float* __restrict__ out) {
    __shared__ float red[256];
    const int t = threadIdx.x;
    red[t] = partials[t] + partials[t + 256] + partials[t + 512] + partials[t + 768];
    __syncthreads();
    for (int off = 128; off > 0; off >>= 1) {
        if (t < off) red[t] += red[t + off];
        __syncthreads();
    }
    if (t == 0) {
        float mean = red[0] / (float)((size_t)N * D);
        out[(size_t)N * D + (size_t)N * K + N] = mean + 0.25f * mean;
    }
}

extern "C" void kernel_launch(void* const* d_in, const int* in_sizes, int n_in,
                              void* d_out, int out_size, void* d_ws, size_t ws_size,
                              hipStream_t stream) {
    const float* X = (const float*)d_in[0];
    const float* E = (const float*)d_in[1];
    float* out = (float*)d_out;
    float* enc = out + (size_t)N * D;
    char* ws = (char*)d_ws;

    const size_t E1T_B = (size_t)K * D * 2;          // 2 MB
    const size_t E2T_B = (size_t)K * D * 4;          // 4 MB
    const bool use_e2t = ws_size >= E1T_B + E2T_B + 512 * 1024;

    unsigned short* e1t = (unsigned short*)ws;
    float* e2t; float* enorm;
    if (use_e2t) {
        e2t = (float*)(ws + E1T_B);
        enorm = (float*)(ws + E1T_B + E2T_B);
    } else {
        e2t = nullptr;
        enorm = (float*)(ws + E1T_B);
    }
    unsigned long long* bestws = (unsigned long long*)((char*)(enorm + K));  // 128 KB
    float* partials = (float*)(bestws + N);                                  // 4 KB

    hipLaunchKernelGGL(prep_kernel, dim3(K / 32), dim3(256), 0, stream,
                       E, e1t, e2t, enorm);
    if (use_e2t) {
        hipLaunchKernelGGL((mega_kernel<1>), dim3(768), dim3(THREADS), 0, stream,
                           X, E, e1t, e2t, enorm, enc, bestws);
        hipLaunchKernelGGL((finish_kernel<1>), dim3(N / 16), dim3(256), 0, stream,
                           X, E, e2t, bestws, out, partials);
    } else {
        hipLaunchKernelGGL((mega_kernel<0>), dim3(768), dim3(THREADS), 0, stream,
                           X, E, e1t, e2t, enorm, enc, bestws);
        hipLaunchKernelGGL((finish_kernel<0>), dim3(N / 16), dim3(256), 0, stream,
                           X, E, e2t, bestws, out, partials);
    }
    hipLaunchKernelGGL(loss_kernel, dim3(1), dim3(256), 0, stream, partials, out);
}